// Round 5
// baseline (85.835 us; speedup 1.0000x reference)
//
#include <hip/hip_runtime.h>
#include <math.h>

// B=8, N=1024, D=128.  kv[b,n,512] = [k_mu | v_mu | k_sigma | v_sigma]
// 2-kernel plan (R5): tail folded into actor via j-full blocks.
//  1) prepass: V side only (cols 128/384) fp32 -> bf16 MFMA-fragment
//     order. b = blockIdx&7 so fragV[b] is written on XCD b -- the same
//     XCD the actor (blockIdx%8==b) reads it from. Seeds log-prob slots.
//  2) actor: S^T = V.K^T. Block = 512 thr (8 waves), 16 i x FULL 1024 j
//     -> no partial/tail: cross-wave combine, inline tanh-normal math,
//     per-block atomicAdd(log_prob). Grid 8b x 64ibx = 512 = 2/CU =
//     16 waves/CU (R4 showed 16 vs 32 waves ~neutral). Wave w walks
//     j-tiles w*8..w*8+7. sK = 1 K tile (8 KB), staged fp32->bf16 in
//     prologue (bit-exact path, verified R1). V from prepass fragV
//     (bf16x8 contiguous; R1: never fp32+cvt in the inner loop).
//     LDS ~20.4 KB (sK 8 + spj 12 + spi); wacc aliases sK after loop.
//     Tail math via ONE __expf + ONE __logf per component:
//       softplus(t)+softplus(-t) = |t| + 2*log(1+E), E=exp(-|t|)
//       tanh(p) = sign(p)*(1-E)/(1+E)   (same E, t=2p)
// NOTE: 512-thread blocks + plain __launch_bounds__(512) (VGPR 52-60,
// no spill). Never the min-waves arg (VGPR=64 clamp + spill) or
// 1024-thr blocks. No __threadfence / cross-block merge (wbl2 storms).
// j-accumulation order changes vs R4 (128 j in-reg per wave, then 8
// waves) -- fp reorder only, bf16 rounding noise dominates (absmax
// pass criterion unchanged across all prior reorders).

#define NTOK 1024
#define LPCONST 14147.0828114f   // -3072*ln(0.01)

typedef __bf16 bf16x8 __attribute__((ext_vector_type(8)));
typedef float f32x4 __attribute__((ext_vector_type(4)));
typedef unsigned short ushort8v __attribute__((ext_vector_type(8)));
#define MFMA(a, b, c) __builtin_amdgcn_mfma_f32_16x16x32_bf16(a, b, c, 0, 0, 0)

__device__ __forceinline__ unsigned short to_bf16(float x) {
    return (unsigned short)((__float_as_uint(x) + 0x8000u) >> 16);
}

__device__ __forceinline__ ushort8v pack8(float4 a, float4 b) {
    ushort8v u;
    u[0] = to_bf16(a.x); u[1] = to_bf16(a.y); u[2] = to_bf16(a.z); u[3] = to_bf16(a.w);
    u[4] = to_bf16(b.x); u[5] = to_bf16(b.y); u[6] = to_bf16(b.z); u[7] = to_bf16(b.w);
    return u;
}

// ---------------- prepass: V side only, XCD-aligned ----------------
__global__ __launch_bounds__(256) void prepass_kernel(
    const float* __restrict__ kv, unsigned short* __restrict__ frag,
    float* __restrict__ out)
{
    if (blockIdx.x == 0 && threadIdx.x < 8)
        out[8 * NTOK * 3 + threadIdx.x] = LPCONST;   // seed log-prob slots

    const int b = blockIdx.x & 7;                    // XCD-local to actor's b
    const int g = (blockIdx.x >> 3) * 256 + threadIdx.x;   // 0..16383 per b
    const int lane = g & 63;
    const int kc   = (g >> 6) & 3;
    const int tile = (g >> 8) & 63;

    const int row = tile * 16 + (lane & 15);
    const int kof = kc * 32 + (lane >> 4) * 8;
    const float* gp = kv + ((size_t)b * NTOK + row) * 512 + 128 + kof;  // v_mu
    const float4 m0 = *(const float4*)gp;
    const float4 m1 = *(const float4*)(gp + 4);
    const float4 s0 = *(const float4*)(gp + 256);   // v_sigma (col 384+kof)
    const float4 s1 = *(const float4*)(gp + 260);

    unsigned short* cp = frag + (size_t)(b * 64 + tile) * 4096 + kc * 1024 + lane * 8;
    *(ushort8v*)(cp + 0)   = pack8(m0, m1);   // arr0 mu
    *(ushort8v*)(cp + 512) = pack8(s0, s1);   // arr1 sg
}

// ------- gemm^T + geometry + tail, 16 i x 1024 j per block -------
__global__ __launch_bounds__(512) void actor_kernel(
    const float* __restrict__ kv, const unsigned short* __restrict__ fragV,
    const float* __restrict__ pos, const float* __restrict__ eps,
    float* __restrict__ out)
{
    const int t = threadIdx.x;
    const int w = t >> 6;        // wave 0..7
    const int lane = t & 63;
    const int q = lane >> 4;
    const int r16 = lane & 15;
    const int b   = blockIdx.x & 7;
    const int ibx = blockIdx.x >> 3;         // 0..63
    const int i0 = ibx * 16;

    const float* kvb  = kv + (size_t)b * NTOK * 512;
    const float* posb = pos + (size_t)b * NTOK * 3;

    __shared__ __align__(16) unsigned short sK[4096];   // 8 KB: 1 K tile; wacc aliases
    __shared__ __align__(16) float spj[NTOK * 3];       // 12 KB: all j positions
    __shared__ __align__(16) float spi[48];             // 16 i positions
    float* wacc = (float*)sK;                           // 768 floats = 3 KB

    // ---- stage K tile: 16 rows x (mu cols 0-127 | sg cols 256-383) ----
    // thread t: row ri = t>>5 (0..15), cg = t&31; arr = cg>>4, c2 = cg&15
    // (8 k-cols each).  frag ushort idx = kc*1024 + arr*512 +
    // (g*16 + ri)*8 + e  with kc = c2>>2, g = c2&3, k = kc*32+g*8+e.
    {
        const int ri  = t >> 5;
        const int cg  = t & 31;
        const int arr = cg >> 4;
        const int c2  = cg & 15;
        const float* gp = kvb + (size_t)(i0 + ri) * 512 + arr * 256 + c2 * 8;
        const float4 a0 = *(const float4*)gp;
        const float4 a1 = *(const float4*)(gp + 4);
        unsigned short* dp = sK + (c2 >> 2) * 1024 + arr * 512
                           + ((c2 & 3) * 16 + ri) * 8;
        *(ushort8v*)dp = pack8(a0, a1);
    }
    for (int u = t; u < 768; u += 512)
        *(float4*)&spj[u * 4] = *(const float4*)&posb[u * 4];
    if (t < 12) *(float4*)&spi[t * 4] = *(const float4*)&posb[i0 * 3 + t * 4];
    __syncthreads();

    const float pix = spi[r16 * 3 + 0];
    const float piy = spi[r16 * 3 + 1];
    const float piz = spi[r16 * 3 + 2];

    float am[3] = {}, al[3] = {};

    const unsigned short* vbase =
        fragV + (size_t)(b * 64 + w * 8) * 4096 + lane * 8;
    const int klofs = lane * 8;

    #pragma unroll 2
    for (int jt = 0; jt < 8; ++jt) {
        const unsigned short* vp = vbase + (size_t)jt * 4096;
        f32x4 accm = (f32x4){0.f, 0.f, 0.f, 0.f};
        f32x4 accs = (f32x4){0.f, 0.f, 0.f, 0.f};
        #pragma unroll
        for (int kc = 0; kc < 4; ++kc) {
            const bf16x8 Vm = *(const bf16x8*)(vp + kc * 1024);
            const bf16x8 Vs = *(const bf16x8*)(vp + kc * 1024 + 512);
            const bf16x8 Km = *(const bf16x8*)&sK[kc * 1024 + klofs];
            const bf16x8 Ks = *(const bf16x8*)&sK[kc * 1024 + 512 + klofs];
            accm = MFMA(Vm, Km, accm);   // C[row=j][col=i]
            accs = MFMA(Vs, Ks, accs);
        }
        // ---- fold this tile's 4 j's (rows q*4+reg) into per-i sums ----
        const int jbase = (w * 8 + jt) * 16 + q * 4;
        #pragma unroll
        for (int reg = 0; reg < 4; ++reg) {
            const float* pj = &spj[(jbase + reg) * 3];  // LDS broadcast
            const float pjx = pj[0], pjy = pj[1], pjz = pj[2];
            const float dx = pix - pjx;
            const float dy = piy - pjy;
            const float dz = piz - pjz;
            const float d2 = dx * dx + dy * dy + dz * dz;
            const float inv = d2 > 0.f ? rsqrtf(d2) : 0.f;  // i==j -> 0
            const float wm = accm[reg] * inv;
            const float ws = accs[reg] * inv;
            am[0] = fmaf(dx, wm, am[0]);
            am[1] = fmaf(dy, wm, am[1]);
            am[2] = fmaf(dz, wm, am[2]);
            al[0] = fmaf(dx, ws, al[0]);
            al[1] = fmaf(dy, ws, al[1]);
            al[2] = fmaf(dz, ws, al[2]);
        }
    }

    // ---- reduce over the 4 q-groups (lanes r16, +16, +32, +48) ----
    #pragma unroll
    for (int c = 0; c < 3; ++c) {
        float vm = am[c], vl = al[c];
        vm += __shfl_xor(vm, 16, 64); vm += __shfl_xor(vm, 32, 64);
        vl += __shfl_xor(vl, 16, 64); vl += __shfl_xor(vl, 32, 64);
        am[c] = vm; al[c] = vl;
    }

    // ---- cross-wave combine via LDS (wacc aliases sK: sync first) ----
    __syncthreads();   // all waves done reading sK before overwrite
    if (lane < 16) {
        float* p = wacc + (w * 16 + r16) * 6;
        p[0] = am[0]; p[1] = am[1]; p[2] = am[2];
        p[3] = al[0]; p[4] = al[1]; p[5] = al[2];
    }
    __syncthreads();

    // ---- inline tail: 48 threads = 16 rows x 3 comps ----
    float lp = 0.f;
    if (t < 48) {
        const int row = t / 3, c = t - row * 3;
        float sam = 0.f, sal = 0.f;
        #pragma unroll
        for (int ww = 0; ww < 8; ++ww) {
            const float* p = wacc + ((ww * 16 + row) * 6);
            sam += p[c];
            sal += p[3 + c];
        }
        const int gi = b * NTOK + i0 + row;
        const float als = fminf(fmaxf(sal, -20.f), 2.f);
        const float sd = __expf(als);
        const float e = eps[gi * 3 + c];
        const float pre = fmaf(sd, e, sam);
        // E = exp(-2|pre|):  tanh(pre) = sign*(1-E)/(1+E);
        // softplus(2pre)+softplus(-2pre) = 2|pre| + 2*log(1+E)
        const float a2 = 2.f * fabsf(pre);
        const float E = __expf(-a2);
        const float th = (1.f - E) / (1.f + E);
        out[gi * 3 + c] = copysignf(th, pre) * 0.01f;
        lp = fmaf(-0.5f * e, e, -als) - 2.3052328944f + a2 + 2.f * __logf(1.f + E);
    }
    if (t < 64) {   // wave 0 only: reduce 48 live lanes + zeros
        #pragma unroll
        for (int m = 1; m < 64; m <<= 1) lp += __shfl_xor(lp, m, 64);
        if (t == 0) atomicAdd(out + NTOK * 8 * 3 + b, lp);
    }
}

extern "C" void kernel_launch(void* const* d_in, const int* in_sizes, int n_in,
                              void* d_out, int out_size, void* d_ws, size_t ws_size,
                              hipStream_t stream) {
    const float* kv = (const float*)d_in[0];
    const float* pos = (const float*)d_in[1];
    const float* eps = (const float*)d_in[2];
    float* out = (float*)d_out;
    unsigned short* fragV = (unsigned short*)d_ws;                // 4 MiB

    prepass_kernel<<<dim3(512), 256, 0, stream>>>(kv, fragV, out);
    actor_kernel<<<dim3(512), 512, 0, stream>>>(kv, fragV, pos, eps, out);
}

// Round 7
// 85.809 us; speedup vs baseline: 1.0003x; 1.0003x over previous
//
#include <hip/hip_runtime.h>
#include <math.h>

// B=8, N=1024, D=128.  kv[b,n,512] = [k_mu | v_mu | k_sigma | v_sigma]
// 3-kernel plan, V-only prepass, 32-i actor blocks (R4 config = best
// measured, 84.3 us; R6/R7 resubmit after container-side bench failure).
//  1) prepass: V side only (cols 128/384) fp32 -> bf16 MFMA-fragment
//     order. b = blockIdx&7 so fragV[b] is written on XCD b -- the same
//     XCD the actor (blockIdx%8==b) reads it from. Seeds log-prob slots.
//  2) actor: S^T = V.K^T. Block = 512 thr (8 waves), 32 i x 256 j (jh
//     quarter), grid 1024 = 4 blocks/CU = 32 waves/CU. sK = 2 K tiles
//     = 16 KB; LDS ~19 KB. K staged fp32->bf16 into MFMA-frag LDS
//     (prologue-only cost, bit-exact, verified R1). V from prepass
//     fragV (bf16x8 contiguous; R1: never fp32+cvt in the inner loop;
//     R5: never drop V-fragment reuse below 4 MFMAs/fragment).
//     C[row=j][col=i]: lane col fixed per tile; 4 regs = 4 j; geometric
//     fold in-register; q-group shuffle; wacc aliases sK; partial.
//  3) tail: 128 blocks x 64 thr; sums 4 jh partials, tanh-normal math
//     via ONE __expf + ONE __logf per component:
//       softplus(t)+softplus(-t) = |t| + 2*log(1+E), E=exp(-|t|)
//       tanh(p) = sign(p)*(1-E)/(1+E)   (same E, t=2p)
//     per-wave log_prob reduce + atomicAdd.
// SESSION FLOOR EVIDENCE (R0-R5): all structural deltas (launch count
// 3->2, occupancy 2x, LDS 56->19 KB, partial round-trip removal) land
// within +-1.5 us noise; only heavy dispatches in rocprof are the
// harness's fixed 256 MiB poison fills at 78-79% HBM peak (= measured
// achievable ceiling). Controllable kernel time ~13-15 us of ~85 total.
// NOTE: 512-thread blocks + plain __launch_bounds__(512) (VGPR 52-60,
// no spill). Never the min-waves arg (VGPR=64 clamp + spill) or
// 1024-thr blocks. No __threadfence / cross-block merge (wbl2 storms).

#define NTOK 1024
#define LPCONST 14147.0828114f   // -3072*ln(0.01)

typedef __bf16 bf16x8 __attribute__((ext_vector_type(8)));
typedef float f32x4 __attribute__((ext_vector_type(4)));
typedef unsigned short ushort8v __attribute__((ext_vector_type(8)));
#define MFMA(a, b, c) __builtin_amdgcn_mfma_f32_16x16x32_bf16(a, b, c, 0, 0, 0)

__device__ __forceinline__ unsigned short to_bf16(float x) {
    return (unsigned short)((__float_as_uint(x) + 0x8000u) >> 16);
}

__device__ __forceinline__ ushort8v pack8(float4 a, float4 b) {
    ushort8v u;
    u[0] = to_bf16(a.x); u[1] = to_bf16(a.y); u[2] = to_bf16(a.z); u[3] = to_bf16(a.w);
    u[4] = to_bf16(b.x); u[5] = to_bf16(b.y); u[6] = to_bf16(b.z); u[7] = to_bf16(b.w);
    return u;
}

// ---------------- prepass: V side only, XCD-aligned ----------------
__global__ __launch_bounds__(256) void prepass_kernel(
    const float* __restrict__ kv, unsigned short* __restrict__ frag,
    float* __restrict__ out)
{
    if (blockIdx.x == 0 && threadIdx.x < 8)
        out[8 * NTOK * 3 + threadIdx.x] = LPCONST;   // seed log-prob slots

    const int b = blockIdx.x & 7;                    // XCD-local to actor's b
    const int g = (blockIdx.x >> 3) * 256 + threadIdx.x;   // 0..16383 per b
    const int lane = g & 63;
    const int kc   = (g >> 6) & 3;
    const int tile = (g >> 8) & 63;

    const int row = tile * 16 + (lane & 15);
    const int kof = kc * 32 + (lane >> 4) * 8;
    const float* gp = kv + ((size_t)b * NTOK + row) * 512 + 128 + kof;  // v_mu
    const float4 m0 = *(const float4*)gp;
    const float4 m1 = *(const float4*)(gp + 4);
    const float4 s0 = *(const float4*)(gp + 256);   // v_sigma (col 384+kof)
    const float4 s1 = *(const float4*)(gp + 260);

    unsigned short* cp = frag + (size_t)(b * 64 + tile) * 4096 + kc * 1024 + lane * 8;
    *(ushort8v*)(cp + 0)   = pack8(m0, m1);   // arr0 mu
    *(ushort8v*)(cp + 512) = pack8(s0, s1);   // arr1 sg
}

// ---------------- gemm^T + geometry, 32 i x 256 j per block ----------------
__global__ __launch_bounds__(512) void actor_kernel(
    const float* __restrict__ kv, const unsigned short* __restrict__ fragV,
    const float* __restrict__ pos, float* __restrict__ partial)
{
    const int t = threadIdx.x;
    const int w = t >> 6;        // wave 0..7
    const int lane = t & 63;
    const int q = lane >> 4;
    const int r16 = lane & 15;
    const int b   = blockIdx.x & 7;
    const int jh  = (blockIdx.x >> 3) & 3;   // j quarter
    const int ibx = blockIdx.x >> 5;         // 0..31
    const int i0 = ibx * 32;

    const float* kvb  = kv + (size_t)b * NTOK * 512;
    const float* posb = pos + (size_t)b * NTOK * 3;

    __shared__ __align__(16) unsigned short sK[8192];   // 16 KB: 2 K tiles; wacc aliases
    __shared__ __align__(16) float spi[32 * 3];         // this block's i-positions
    __shared__ __align__(16) float spj[256 * 3];        // this block's j-quarter positions
    float* wacc = (float*)sK;                           // 8*32*6 = 1536 floats = 6 KB

    // ---- stage K: fp32 rows -> bf16 MFMA-fragment order in LDS ----
    // thread t -> row ri = t>>4 (0..31), col-group cg = t&15 (8 cols).
    // k-cols cg*8..+7: kc = cg>>2, g = cg&3; frag ushort idx =
    // tile*4096 + kc*1024 + arr*512 + (g*16 + row%16)*8 + e.
    {
        const int ri = t >> 4;
        const int cg = t & 15;
        const float* gp = kvb + (size_t)(i0 + ri) * 512 + cg * 8;
        const float4 m0 = *(const float4*)(gp);
        const float4 m1 = *(const float4*)(gp + 4);
        const float4 s0 = *(const float4*)(gp + 256);
        const float4 s1 = *(const float4*)(gp + 260);
        unsigned short* dp = sK + (ri >> 4) * 4096 + (cg >> 2) * 1024
                           + ((cg & 3) * 16 + (ri & 15)) * 8;
        *(ushort8v*)(dp)       = pack8(m0, m1);   // arr0 mu
        *(ushort8v*)(dp + 512) = pack8(s0, s1);   // arr1 sg
    }
    // ---- stage only the positions this block touches ----
    if (t < 216) {
        if (t < 24)  *(float4*)&spi[t * 4] = *(const float4*)&posb[i0 * 3 + t * 4];
        else { const int v = t - 24;
               *(float4*)&spj[v * 4] = *(const float4*)&posb[jh * 768 + v * 4]; }
    }
    __syncthreads();

    // lane's i per tile (C column) is fixed
    float pix[2], piy[2], piz[2];
    #pragma unroll
    for (int tile = 0; tile < 2; ++tile) {
        pix[tile] = spi[(tile * 16 + r16) * 3 + 0];
        piy[tile] = spi[(tile * 16 + r16) * 3 + 1];
        piz[tile] = spi[(tile * 16 + r16) * 3 + 2];
    }

    float am[2][3] = {};   // [tile][c]
    float al[2][3] = {};

    const int jtile0 = jh * 16 + w * 2;   // this wave's first 16-j tile
    const unsigned short* vbase =
        fragV + (size_t)(b * 64 + jtile0) * 4096 + lane * 8;
    const int klofs = lane * 8;

    #pragma unroll
    for (int jt = 0; jt < 2; ++jt) {
        const unsigned short* vp = vbase + jt * 4096;
        f32x4 accm[2], accs[2];
        #pragma unroll
        for (int tile = 0; tile < 2; ++tile) {
            accm[tile] = (f32x4){0.f, 0.f, 0.f, 0.f};
            accs[tile] = (f32x4){0.f, 0.f, 0.f, 0.f};
        }
        #pragma unroll
        for (int kc = 0; kc < 4; ++kc) {
            const bf16x8 Vm = *(const bf16x8*)(vp + kc * 1024);
            const bf16x8 Vs = *(const bf16x8*)(vp + kc * 1024 + 512);
            #pragma unroll
            for (int tile = 0; tile < 2; ++tile) {
                const bf16x8 Km = *(const bf16x8*)&sK[tile * 4096 + kc * 1024 + klofs];
                const bf16x8 Ks = *(const bf16x8*)&sK[tile * 4096 + kc * 1024 + 512 + klofs];
                accm[tile] = MFMA(Vm, Km, accm[tile]);   // C[row=j][col=i]
                accs[tile] = MFMA(Vs, Ks, accs[tile]);
            }
        }
        // ---- fold this tile's 4 j's (rows q*4+reg) into per-i sums ----
        const int jl = (w * 2 + jt) * 16 + q * 4;   // local j in [0,256)
        #pragma unroll
        for (int reg = 0; reg < 4; ++reg) {
            const float* pj = &spj[(jl + reg) * 3];  // LDS broadcast
            const float pjx = pj[0], pjy = pj[1], pjz = pj[2];
            #pragma unroll
            for (int tile = 0; tile < 2; ++tile) {
                const float dx = pix[tile] - pjx;
                const float dy = piy[tile] - pjy;
                const float dz = piz[tile] - pjz;
                const float d2 = dx * dx + dy * dy + dz * dz;
                const float inv = d2 > 0.f ? rsqrtf(d2) : 0.f;  // i==j -> 0
                const float wm = accm[tile][reg] * inv;
                const float ws = accs[tile][reg] * inv;
                am[tile][0] = fmaf(dx, wm, am[tile][0]);
                am[tile][1] = fmaf(dy, wm, am[tile][1]);
                am[tile][2] = fmaf(dz, wm, am[tile][2]);
                al[tile][0] = fmaf(dx, ws, al[tile][0]);
                al[tile][1] = fmaf(dy, ws, al[tile][1]);
                al[tile][2] = fmaf(dz, ws, al[tile][2]);
            }
        }
    }

    // ---- reduce over the 4 q-groups (lanes r16, +16, +32, +48) ----
    #pragma unroll
    for (int tile = 0; tile < 2; ++tile)
        #pragma unroll
        for (int c = 0; c < 3; ++c) {
            float vm = am[tile][c], vl = al[tile][c];
            vm += __shfl_xor(vm, 16, 64); vm += __shfl_xor(vm, 32, 64);
            vl += __shfl_xor(vl, 16, 64); vl += __shfl_xor(vl, 32, 64);
            am[tile][c] = vm; al[tile][c] = vl;
        }

    // ---- cross-wave combine via LDS (wacc aliases sK: sync first) ----
    __syncthreads();   // all waves done reading sK before overwrite
    if (lane < 16) {
        #pragma unroll
        for (int tile = 0; tile < 2; ++tile) {
            float* p = wacc + (w * 32 + tile * 16 + r16) * 6;
            p[0] = am[tile][0]; p[1] = am[tile][1]; p[2] = am[tile][2];
            p[3] = al[tile][0]; p[4] = al[tile][1]; p[5] = al[tile][2];
        }
    }
    __syncthreads();
    if (t < 192) {
        float v = 0.f;
        #pragma unroll
        for (int ww = 0; ww < 8; ++ww) v += wacc[ww * 192 + t];
        const int row = t / 6, c = t - row * 6;
        partial[((size_t)((jh * 8 + b) * NTOK) + i0 + row) * 6 + c] = v;
    }
}

// ---------------- tail ----------------
__global__ __launch_bounds__(64) void actor_tail_kernel(
    const float* __restrict__ partial, const float* __restrict__ eps,
    float* __restrict__ out)
{
    const int b = blockIdx.x >> 4;
    const int i = (blockIdx.x & 15) * 64 + threadIdx.x;
    const int gi = b * NTOK + i;

    float am[3] = {}, al[3] = {};
    #pragma unroll
    for (int jh = 0; jh < 4; ++jh) {
        const float* p = partial + (((size_t)jh * 8 + b) * NTOK + i) * 6;
        const float2 v0 = *(const float2*)(p);
        const float2 v1 = *(const float2*)(p + 2);
        const float2 v2 = *(const float2*)(p + 4);
        am[0] += v0.x; am[1] += v0.y; am[2] += v1.x;
        al[0] += v1.y; al[1] += v2.x; al[2] += v2.y;
    }

    float lp = 0.f;
    #pragma unroll
    for (int c = 0; c < 3; ++c) {
        const float als = fminf(fmaxf(al[c], -20.f), 2.f);
        const float sd = __expf(als);
        const float e = eps[gi * 3 + c];
        const float pre = fmaf(sd, e, am[c]);
        // E = exp(-2|pre|):  tanh(pre) = sign*(1-E)/(1+E);
        // softplus(2pre)+softplus(-2pre) = 2|pre| + 2*log(1+E)
        const float a2 = 2.f * fabsf(pre);
        const float E = __expf(-a2);
        const float th = (1.f - E) / (1.f + E);
        out[gi * 3 + c] = copysignf(th, pre) * 0.01f;
        lp += fmaf(-0.5f * e, e, -als) - 2.3052328944f + a2 + 2.f * __logf(1.f + E);
    }

    #pragma unroll
    for (int m = 1; m < 64; m <<= 1) lp += __shfl_xor(lp, m, 64);
    if (threadIdx.x == 0) atomicAdd(out + NTOK * 8 * 3 + b, lp);
}

extern "C" void kernel_launch(void* const* d_in, const int* in_sizes, int n_in,
                              void* d_out, int out_size, void* d_ws, size_t ws_size,
                              hipStream_t stream) {
    const float* kv = (const float*)d_in[0];
    const float* pos = (const float*)d_in[1];
    const float* eps = (const float*)d_in[2];
    float* out = (float*)d_out;
    unsigned short* fragV = (unsigned short*)d_ws;                // 4 MiB
    float* partial = (float*)((char*)d_ws + 4194304);             // 768 KiB

    prepass_kernel<<<dim3(512), 256, 0, stream>>>(kv, fragV, out);
    actor_kernel<<<dim3(1024), 512, 0, stream>>>(kv, fragV, pos, partial);
    actor_tail_kernel<<<dim3(128), 64, 0, stream>>>(partial, eps, out);
}